// Round 1
// baseline (3627.897 us; speedup 1.0000x reference)
//
#include <hip/hip_runtime.h>

#define FD 128          // feature dim
#define EPSN 1e-8f      // laplace eps
#define RCC 0.5f        // residual coeff

// ---------------- degree / dinv ----------------
__global__ void deg_kernel(const int* __restrict__ u, const int* __restrict__ v,
                           int na, int E, int* __restrict__ deg) {
    int e = blockIdx.x * blockDim.x + threadIdx.x;
    if (e >= E) return;
    atomicAdd(&deg[u[e]], 1);
    atomicAdd(&deg[v[e] + na], 1);
}

__global__ void dinv_kernel(const int* __restrict__ deg, float* __restrict__ dinv, int n) {
    int i = blockIdx.x * blockDim.x + threadIdx.x;
    if (i >= n) return;
    dinv[i] = 1.0f / (sqrtf((float)deg[i]) + EPSN);
}

__device__ __forceinline__ float wave_sum(float x) {
#pragma unroll
    for (int off = 32; off > 0; off >>= 1) x += __shfl_xor(x, off);
    return x;
}

// ---------------- init: fcur=feats, fini=l2norm(feats), facc=feats ----------------
__global__ void init_kernel(const float* __restrict__ af, const float* __restrict__ bf,
                            int na, int n, float* __restrict__ fcur,
                            float* __restrict__ fini, float* __restrict__ facc) {
    int w = (blockIdx.x * blockDim.x + threadIdx.x) >> 6;
    int lane = threadIdx.x & 63;
    if (w >= n) return;
    const float* src = (w < na) ? (af + (size_t)w * FD) : (bf + (size_t)(w - na) * FD);
    float2 x = ((const float2*)src)[lane];
    float ss = wave_sum(x.x * x.x + x.y * x.y);
    float inv = 1.0f / fmaxf(sqrtf(ss), 1e-12f);
    ((float2*)(fcur + (size_t)w * FD))[lane] = x;
    float2 xi = make_float2(x.x * inv, x.y * inv);
    ((float2*)(fini + (size_t)w * FD))[lane] = xi;
    ((float2*)(facc + (size_t)w * FD))[lane] = x;
}

// ---------------- SpMM: one wave per undirected edge, both directions, atomic scatter ----------------
__global__ void spmm_edges(const int* __restrict__ u, const int* __restrict__ v,
                           int na, int E, const float* __restrict__ dinv,
                           const float* __restrict__ fin, float* __restrict__ fout) {
    int w = (blockIdx.x * blockDim.x + threadIdx.x) >> 6;
    int lane = threadIdx.x & 63;
    if (w >= E) return;
    int a = u[w];
    int b = v[w] + na;
    float wt = dinv[a] * dinv[b];
    float2 xa = ((const float2*)(fin + (size_t)a * FD))[lane];
    float2 xb = ((const float2*)(fin + (size_t)b * FD))[lane];
    float* oa = fout + (size_t)a * FD + lane * 2;
    float* ob = fout + (size_t)b * FD + lane * 2;
    atomicAdd(oa,     wt * xb.x);
    atomicAdd(oa + 1, wt * xb.y);
    atomicAdd(ob,     wt * xa.x);
    atomicAdd(ob + 1, wt * xa.y);
}

// ---------------- post: v=(tmp+RC*ini)*sc; l2norm; fcur=v; facc+=v ----------------
__global__ void post_kernel(const float* __restrict__ ftmp, const float* __restrict__ fini,
                            float sc, float* __restrict__ fcur, float* __restrict__ facc, int n) {
    int w = (blockIdx.x * blockDim.x + threadIdx.x) >> 6;
    int lane = threadIdx.x & 63;
    if (w >= n) return;
    float2 t  = ((const float2*)(ftmp + (size_t)w * FD))[lane];
    float2 i0 = ((const float2*)(fini + (size_t)w * FD))[lane];
    float2 vv = make_float2((t.x + RCC * i0.x) * sc, (t.y + RCC * i0.y) * sc);
    float ss = wave_sum(vv.x * vv.x + vv.y * vv.y);
    float inv = 1.0f / fmaxf(sqrtf(ss), 1e-12f);
    vv.x *= inv; vv.y *= inv;
    ((float2*)(fcur + (size_t)w * FD))[lane] = vv;
    float2* pa = (float2*)(facc + (size_t)w * FD);
    float2 a0 = pa[lane];
    pa[lane] = make_float2(a0.x + vv.x, a0.y + vv.y);
}

// ---------------- writeout UB acc: users -> out[NU..2NU), bundles -> out[2NU+NB..) ----------------
__global__ void writeout_ub(const float* __restrict__ facc, float* __restrict__ out,
                            int NU, int NB, int n) {
    int w = (blockIdx.x * blockDim.x + threadIdx.x) >> 6;
    int lane = threadIdx.x & 63;
    if (w >= n) return;
    size_t dst = (w < NU) ? (size_t)(NU + w) : (size_t)(2 * NU + NB + (w - NU));
    float2 x = ((const float2*)(facc + (size_t)w * FD))[lane];
    ((float2*)(out + dst * FD))[lane] = x;
}

// ---------------- writeout UI acc (users part only): -> out[0..NU) ----------------
__global__ void writeout_ui(const float* __restrict__ facc, float* __restrict__ out, int NU) {
    int w = (blockIdx.x * blockDim.x + threadIdx.x) >> 6;
    int lane = threadIdx.x & 63;
    if (w >= NU) return;
    float2 x = ((const float2*)(facc + (size_t)w * FD))[lane];
    ((float2*)(out + (size_t)w * FD))[lane] = x;
}

// ---------------- BI: out[2NU+b] += val * ui_items[i]  (ui_items = facc rows NU..NU+NI) ----------------
__global__ void bi_kernel(const int* __restrict__ bb, const int* __restrict__ bi,
                          const float* __restrict__ vals, const float* __restrict__ facc,
                          float* __restrict__ out, int NU, int E) {
    int w = (blockIdx.x * blockDim.x + threadIdx.x) >> 6;
    int lane = threadIdx.x & 63;
    if (w >= E) return;
    int b = bb[w];
    int it = bi[w];
    float val = vals[w];
    float2 x = ((const float2*)(facc + (size_t)(NU + it) * FD))[lane];
    float* dst = out + (size_t)(2 * NU + b) * FD + lane * 2;
    atomicAdd(dst,     val * x.x);
    atomicAdd(dst + 1, val * x.y);
}

extern "C" void kernel_launch(void* const* d_in, const int* in_sizes, int n_in,
                              void* d_out, int out_size, void* d_ws, size_t ws_size,
                              hipStream_t stream) {
    const float* users   = (const float*)d_in[0];
    const float* bundles = (const float*)d_in[1];
    const float* items   = (const float*)d_in[2];
    const float* bi_vals = (const float*)d_in[3];
    const int* ub_u = (const int*)d_in[4];
    const int* ub_b = (const int*)d_in[5];
    const int* ui_u = (const int*)d_in[6];
    const int* ui_i = (const int*)d_in[7];
    const int* bi_b = (const int*)d_in[8];
    const int* bi_i = (const int*)d_in[9];

    const int NU = in_sizes[0] / FD;
    const int NB = in_sizes[1] / FD;
    const int NI = in_sizes[2] / FD;
    const int E_BI = in_sizes[3];
    const int E_UB = in_sizes[4];
    const int E_UI = in_sizes[6];
    float* out = (float*)d_out;

    const int n1 = NU + NB, n2 = NU + NI;
    const int NMAX = (n1 > n2) ? n1 : n2;
    float* fcur = (float*)d_ws;
    float* fini = fcur + (size_t)NMAX * FD;
    float* ftmp = fini + (size_t)NMAX * FD;
    float* facc = ftmp + (size_t)NMAX * FD;
    float* dinv = facc + (size_t)NMAX * FD;
    int*   deg  = (int*)(dinv + NMAX);

    dim3 blk(256);
    auto rows_grid = [](int n) { return dim3((unsigned)((n + 3) / 4)); };
    auto thr_grid  = [](int n) { return dim3((unsigned)((n + 255) / 256)); };

    // ===== UB propagation =====
    hipMemsetAsync(deg, 0, (size_t)n1 * 4, stream);
    deg_kernel<<<thr_grid(E_UB), blk, 0, stream>>>(ub_u, ub_b, NU, E_UB, deg);
    dinv_kernel<<<thr_grid(n1), blk, 0, stream>>>(deg, dinv, n1);
    init_kernel<<<rows_grid(n1), blk, 0, stream>>>(users, bundles, NU, n1, fcur, fini, facc);
    for (int i = 0; i < 2; ++i) {
        hipMemsetAsync(ftmp, 0, (size_t)n1 * FD * 4, stream);
        spmm_edges<<<rows_grid(E_UB), blk, 0, stream>>>(ub_u, ub_b, NU, E_UB, dinv, fcur, ftmp);
        post_kernel<<<rows_grid(n1), blk, 0, stream>>>(ftmp, fini, 1.0f / (float)(i + 2), fcur, facc, n1);
    }
    writeout_ub<<<rows_grid(n1), blk, 0, stream>>>(facc, out, NU, NB, n1);

    // ===== UI propagation =====
    hipMemsetAsync(deg, 0, (size_t)n2 * 4, stream);
    deg_kernel<<<thr_grid(E_UI), blk, 0, stream>>>(ui_u, ui_i, NU, E_UI, deg);
    dinv_kernel<<<thr_grid(n2), blk, 0, stream>>>(deg, dinv, n2);
    init_kernel<<<rows_grid(n2), blk, 0, stream>>>(users, items, NU, n2, fcur, fini, facc);
    for (int i = 0; i < 2; ++i) {
        hipMemsetAsync(ftmp, 0, (size_t)n2 * FD * 4, stream);
        spmm_edges<<<rows_grid(E_UI), blk, 0, stream>>>(ui_u, ui_i, NU, E_UI, dinv, fcur, ftmp);
        post_kernel<<<rows_grid(n2), blk, 0, stream>>>(ftmp, fini, 1.0f / (float)(i + 2), fcur, facc, n2);
    }
    writeout_ui<<<rows_grid(NU), blk, 0, stream>>>(facc, out, NU);

    // ===== BI aggregation into out[2NU .. 2NU+NB) =====
    hipMemsetAsync(out + (size_t)2 * NU * FD, 0, (size_t)NB * FD * sizeof(float), stream);
    bi_kernel<<<rows_grid(E_BI), blk, 0, stream>>>(bi_b, bi_i, bi_vals, facc, out, NU, E_BI);
}

// Round 2
// 1143.725 us; speedup vs baseline: 3.1720x; 3.1720x over previous
//
#include <hip/hip_runtime.h>

#define FD 128          // feature dim
#define EPSN 1e-8f      // laplace eps
#define RCC 0.5f        // residual coeff
#define SCAN_TPB 256
#define SCAN_ELEMS 1024 // 4 per thread

// ---------------- degree ----------------
__global__ void deg2_kernel(const int* __restrict__ u, const int* __restrict__ v,
                            int na, int E, int* __restrict__ deg) {
    int e = blockIdx.x * blockDim.x + threadIdx.x;
    if (e >= E) return;
    atomicAdd(&deg[u[e]], 1);
    atomicAdd(&deg[v[e] + na], 1);
}

__global__ void deg1_kernel(const int* __restrict__ r, int E, int* __restrict__ deg) {
    int e = blockIdx.x * blockDim.x + threadIdx.x;
    if (e >= E) return;
    atomicAdd(&deg[r[e]], 1);
}

__global__ void dinv_kernel(const int* __restrict__ deg, float* __restrict__ dinv, int n) {
    int i = blockIdx.x * blockDim.x + threadIdx.x;
    if (i >= n) return;
    dinv[i] = 1.0f / (sqrtf((float)deg[i]) + EPSN);
}

// ---------------- exclusive scan (3 kernels) ----------------
__global__ void scan_a(const int* __restrict__ in, int* __restrict__ out,
                       int* __restrict__ bsum, int nelem) {
    __shared__ int tsum[SCAN_TPB];
    int tid = threadIdx.x;
    int base = blockIdx.x * SCAN_ELEMS + tid * 4;
    int v0 = (base + 0 < nelem) ? in[base + 0] : 0;
    int v1 = (base + 1 < nelem) ? in[base + 1] : 0;
    int v2 = (base + 2 < nelem) ? in[base + 2] : 0;
    int v3 = (base + 3 < nelem) ? in[base + 3] : 0;
    int s = v0 + v1 + v2 + v3;
    tsum[tid] = s;
    __syncthreads();
    for (int off = 1; off < SCAN_TPB; off <<= 1) {
        int y = (tid >= off) ? tsum[tid - off] : 0;
        __syncthreads();
        tsum[tid] += y;
        __syncthreads();
    }
    int excl = tsum[tid] - s;
    if (tid == SCAN_TPB - 1) bsum[blockIdx.x] = tsum[SCAN_TPB - 1];
    if (base + 0 < nelem) out[base + 0] = excl;
    excl += v0;
    if (base + 1 < nelem) out[base + 1] = excl;
    excl += v1;
    if (base + 2 < nelem) out[base + 2] = excl;
    excl += v2;
    if (base + 3 < nelem) out[base + 3] = excl;
}

__global__ void scan_b(int* __restrict__ bsum, int nb) {
    if (threadIdx.x == 0 && blockIdx.x == 0) {
        int run = 0;
        for (int i = 0; i < nb; ++i) { int v = bsum[i]; bsum[i] = run; run += v; }
    }
}

__global__ void scan_c(int* __restrict__ out, const int* __restrict__ bsum, int nelem) {
    int base = blockIdx.x * SCAN_ELEMS + threadIdx.x * 4;
    int add = bsum[blockIdx.x];
#pragma unroll
    for (int k = 0; k < 4; ++k)
        if (base + k < nelem) out[base + k] += add;
}

// ---------------- CSR build ----------------
__global__ void build2_kernel(const int* __restrict__ u, const int* __restrict__ v,
                              int na, int E, int* __restrict__ cursor, int* __restrict__ cols) {
    int e = blockIdx.x * blockDim.x + threadIdx.x;
    if (e >= E) return;
    int a = u[e];
    int b = v[e] + na;
    int pa = atomicAdd(&cursor[a], 1);
    cols[pa] = b;
    int pb = atomicAdd(&cursor[b], 1);
    cols[pb] = a;
}

__global__ void build1_kernel(const int* __restrict__ rr, const int* __restrict__ cc,
                              const float* __restrict__ vals, int E,
                              int* __restrict__ cursor, int* __restrict__ cols,
                              float* __restrict__ wts) {
    int e = blockIdx.x * blockDim.x + threadIdx.x;
    if (e >= E) return;
    int b = rr[e];
    int pos = atomicAdd(&cursor[b], 1);
    cols[pos] = cc[e];
    wts[pos] = vals[e];
}

__device__ __forceinline__ float wave_sum(float x) {
#pragma unroll
    for (int off = 32; off > 0; off >>= 1) x += __shfl_xor(x, off);
    return x;
}

// ---------------- init: fini = l2norm(feats), facc = feats ----------------
__global__ void init_kernel(const float* __restrict__ af, const float* __restrict__ bf,
                            int na, int n, float* __restrict__ fini, float* __restrict__ facc) {
    int w = (blockIdx.x * blockDim.x + threadIdx.x) >> 6;
    int lane = threadIdx.x & 63;
    if (w >= n) return;
    const float* src = (w < na) ? (af + (size_t)w * FD) : (bf + (size_t)(w - na) * FD);
    float2 x = ((const float2*)src)[lane];
    float ss = wave_sum(x.x * x.x + x.y * x.y);
    float inv = 1.0f / fmaxf(sqrtf(ss), 1e-12f);
    ((float2*)(facc + (size_t)w * FD))[lane] = x;
    ((float2*)(fini + (size_t)w * FD))[lane] = make_float2(x.x * inv, x.y * inv);
}

// ---------------- fused gather SpMM + post + (optional) writeout ----------------
// mode 0: write fout = v, facc += v
// mode 1 (UB final): out[NU+w] (users) / out[2NU+NB+(w-NU)] (bundles) = facc + v
// mode 2 (UI final): out[w] = facc + v for users; facc += v for items
__global__ void spmm_fused(const int* __restrict__ rowptr, const int* __restrict__ cols,
                           const float* __restrict__ dinv,
                           const float* __restrict__ af, const float* __restrict__ bf,
                           const float* __restrict__ fin, int split, int na,
                           const float* __restrict__ fini, float* __restrict__ fout,
                           float* __restrict__ facc, float sc, int n,
                           int mode, int NU, int NB2, float* __restrict__ outp) {
    int w = (blockIdx.x * blockDim.x + threadIdx.x) >> 6;
    int lane = threadIdx.x & 63;
    if (w >= n) return;
    int s = rowptr[w];
    int e = rowptr[w + 1];
    float dr = dinv[w];
    // neighbors of row w are all on the opposite side -> wave-uniform base
    const float* nbase = split ? ((w < na) ? (bf - (size_t)na * FD) : af) : fin;
    float ax = 0.0f, ay = 0.0f;
    for (int j = s; j < e; ++j) {
        int c = cols[j];
        float wt = dr * dinv[c];
        float2 x = ((const float2*)(nbase + (size_t)c * FD))[lane];
        ax = fmaf(wt, x.x, ax);
        ay = fmaf(wt, x.y, ay);
    }
    float2 i0 = ((const float2*)(fini + (size_t)w * FD))[lane];
    float vx = (ax + RCC * i0.x) * sc;
    float vy = (ay + RCC * i0.y) * sc;
    float ss = wave_sum(vx * vx + vy * vy);
    float inv = 1.0f / fmaxf(sqrtf(ss), 1e-12f);
    vx *= inv; vy *= inv;
    float2* pa = (float2*)(facc + (size_t)w * FD);
    float2 a0 = pa[lane];
    float2 anew = make_float2(a0.x + vx, a0.y + vy);
    if (mode == 0) {
        ((float2*)(fout + (size_t)w * FD))[lane] = make_float2(vx, vy);
        pa[lane] = anew;
    } else if (mode == 1) {
        size_t dst = (w < NU) ? (size_t)(NU + w) : (size_t)(2 * NU + NB2 + (w - NU));
        ((float2*)(outp + dst * FD))[lane] = anew;
    } else {
        if (w < NU) ((float2*)(outp + (size_t)w * FD))[lane] = anew;
        else        pa[lane] = anew;
    }
}

// ---------------- BI gather: outb[b] = sum val * items[i] ----------------
__global__ void bi_gather(const int* __restrict__ rowptr, const int* __restrict__ cols,
                          const float* __restrict__ wts, const float* __restrict__ items,
                          float* __restrict__ outb, int nb) {
    int w = (blockIdx.x * blockDim.x + threadIdx.x) >> 6;
    int lane = threadIdx.x & 63;
    if (w >= nb) return;
    int s = rowptr[w];
    int e = rowptr[w + 1];
    float ax = 0.0f, ay = 0.0f;
    for (int j = s; j < e; ++j) {
        int c = cols[j];
        float wt = wts[j];
        float2 x = ((const float2*)(items + (size_t)c * FD))[lane];
        ax = fmaf(wt, x.x, ax);
        ay = fmaf(wt, x.y, ay);
    }
    ((float2*)(outb + (size_t)w * FD))[lane] = make_float2(ax, ay);
}

extern "C" void kernel_launch(void* const* d_in, const int* in_sizes, int n_in,
                              void* d_out, int out_size, void* d_ws, size_t ws_size,
                              hipStream_t stream) {
    const float* users   = (const float*)d_in[0];
    const float* bundles = (const float*)d_in[1];
    const float* items   = (const float*)d_in[2];
    const float* bi_vals = (const float*)d_in[3];
    const int* ub_u = (const int*)d_in[4];
    const int* ub_b = (const int*)d_in[5];
    const int* ui_u = (const int*)d_in[6];
    const int* ui_i = (const int*)d_in[7];
    const int* bi_b = (const int*)d_in[8];
    const int* bi_i = (const int*)d_in[9];

    const int NU = in_sizes[0] / FD;
    const int NB = in_sizes[1] / FD;
    const int NI = in_sizes[2] / FD;
    const int E_BI = in_sizes[3];
    const int E_UB = in_sizes[4];
    const int E_UI = in_sizes[6];
    float* out = (float*)d_out;

    const int n1 = NU + NB, n2 = NU + NI;
    const int NMAX = (n1 > n2) ? n1 : n2;
    int CMAX = 2 * E_UB;
    if (2 * E_UI > CMAX) CMAX = 2 * E_UI;
    if (E_BI > CMAX) CMAX = E_BI;

    float* fini = (float*)d_ws;                          // NMAX*FD
    float* facc = fini + (size_t)NMAX * FD;              // NMAX*FD
    float* fX   = facc + (size_t)NMAX * FD;              // NMAX*FD
    float* dinv = fX   + (size_t)NMAX * FD;              // NMAX
    float* wts  = dinv + NMAX;                           // E_BI
    int* deg    = (int*)(wts + E_BI);                    // NMAX+1
    int* rowptr = deg + (NMAX + 1);                      // NMAX+1
    int* cursor = rowptr + (NMAX + 1);                   // NMAX+1
    int* bsum   = cursor + (NMAX + 1);                   // 512
    int* cols   = bsum + 512;                            // CMAX

    dim3 blk(256);
    auto rows_grid = [](int n) { return dim3((unsigned)((n + 3) / 4)); };
    auto thr_grid  = [](int n) { return dim3((unsigned)((n + 255) / 256)); };

    auto run_scan = [&](int n_nodes) {  // deg[0..n_nodes-1] -> rowptr exclusive, rowptr[n]=total
        int nelem = n_nodes + 1;
        int nblk = (nelem + SCAN_ELEMS - 1) / SCAN_ELEMS;
        scan_a<<<dim3((unsigned)nblk), dim3(SCAN_TPB), 0, stream>>>(deg, rowptr, bsum, nelem);
        scan_b<<<dim3(1), dim3(64), 0, stream>>>(bsum, nblk);
        scan_c<<<dim3((unsigned)nblk), dim3(SCAN_TPB), 0, stream>>>(rowptr, bsum, nelem);
        hipMemcpyAsync(cursor, rowptr, (size_t)n_nodes * 4, hipMemcpyDeviceToDevice, stream);
    };

    // ===== UB propagation (final fused -> out rows [NU,2NU) and [2NU+NB, 2NU+2NB)) =====
    hipMemsetAsync(deg, 0, (size_t)(n1 + 1) * 4, stream);
    deg2_kernel<<<thr_grid(E_UB), blk, 0, stream>>>(ub_u, ub_b, NU, E_UB, deg);
    dinv_kernel<<<thr_grid(n1), blk, 0, stream>>>(deg, dinv, n1);
    run_scan(n1);
    build2_kernel<<<thr_grid(E_UB), blk, 0, stream>>>(ub_u, ub_b, NU, E_UB, cursor, cols);
    init_kernel<<<rows_grid(n1), blk, 0, stream>>>(users, bundles, NU, n1, fini, facc);
    spmm_fused<<<rows_grid(n1), blk, 0, stream>>>(rowptr, cols, dinv, users, bundles,
        nullptr, 1, NU, fini, fX, facc, 0.5f, n1, 0, NU, NB, out);
    spmm_fused<<<rows_grid(n1), blk, 0, stream>>>(rowptr, cols, dinv, nullptr, nullptr,
        fX, 0, NU, fini, nullptr, facc, 1.0f / 3.0f, n1, 1, NU, NB, out);

    // ===== UI propagation (final fused -> out rows [0,NU); items acc stays in facc) =====
    hipMemsetAsync(deg, 0, (size_t)(n2 + 1) * 4, stream);
    deg2_kernel<<<thr_grid(E_UI), blk, 0, stream>>>(ui_u, ui_i, NU, E_UI, deg);
    dinv_kernel<<<thr_grid(n2), blk, 0, stream>>>(deg, dinv, n2);
    run_scan(n2);
    build2_kernel<<<thr_grid(E_UI), blk, 0, stream>>>(ui_u, ui_i, NU, E_UI, cursor, cols);
    init_kernel<<<rows_grid(n2), blk, 0, stream>>>(users, items, NU, n2, fini, facc);
    spmm_fused<<<rows_grid(n2), blk, 0, stream>>>(rowptr, cols, dinv, users, items,
        nullptr, 1, NU, fini, fX, facc, 0.5f, n2, 0, NU, NB, out);
    spmm_fused<<<rows_grid(n2), blk, 0, stream>>>(rowptr, cols, dinv, nullptr, nullptr,
        fX, 0, NU, fini, nullptr, facc, 1.0f / 3.0f, n2, 2, NU, NB, out);

    // ===== BI aggregation -> out rows [2NU, 2NU+NB) =====
    hipMemsetAsync(deg, 0, (size_t)(NB + 1) * 4, stream);
    deg1_kernel<<<thr_grid(E_BI), blk, 0, stream>>>(bi_b, E_BI, deg);
    run_scan(NB);
    build1_kernel<<<thr_grid(E_BI), blk, 0, stream>>>(bi_b, bi_i, bi_vals, E_BI, cursor, cols, wts);
    bi_gather<<<rows_grid(NB), blk, 0, stream>>>(rowptr, cols, wts,
        facc + (size_t)NU * FD, out + (size_t)2 * NU * FD, NB);
}

// Round 3
// 932.943 us; speedup vs baseline: 3.8887x; 1.2259x over previous
//
#include <hip/hip_runtime.h>

#define FD   128        // feature dim (floats)
#define FDH  64         // uints per row when stored as bf16x2
#define EPSN 1e-8f
#define RCC  0.5f
#define SCAN_TPB 256
#define SCAN_ELEMS 1024

typedef unsigned int uint;

__device__ __forceinline__ float wave_sum(float x) {
#pragma unroll
    for (int off = 32; off > 0; off >>= 1) x += __shfl_xor(x, off);
    return x;
}

__device__ __forceinline__ uint packbf2(float a, float b) {
    uint ua = __float_as_uint(a); ua += 0x7fffu + ((ua >> 16) & 1u);
    uint ub = __float_as_uint(b); ub += 0x7fffu + ((ub >> 16) & 1u);
    return (ua >> 16) | (ub & 0xffff0000u);
}
__device__ __forceinline__ float2 unpackbf2(uint v) {
    return make_float2(__uint_as_float(v << 16), __uint_as_float(v & 0xffff0000u));
}

// ---------------- merged degree over all three graphs ----------------
__global__ void deg_all(const int* __restrict__ ub_u, const int* __restrict__ ub_b,
                        const int* __restrict__ ui_u, const int* __restrict__ ui_i,
                        const int* __restrict__ bi_b,
                        int E_UB, int E_UI, int E_BI, int NU, int n1, int n2,
                        int* __restrict__ deg) {
    int e = blockIdx.x * blockDim.x + threadIdx.x;
    if (e < E_UB) {
        atomicAdd(&deg[ub_u[e]], 1);
        atomicAdd(&deg[ub_b[e] + NU], 1);
    } else if (e < E_UB + E_UI) {
        int f = e - E_UB;
        atomicAdd(&deg[n1 + ui_u[f]], 1);
        atomicAdd(&deg[n1 + NU + ui_i[f]], 1);
    } else if (e < E_UB + E_UI + E_BI) {
        int f = e - E_UB - E_UI;
        atomicAdd(&deg[n1 + n2 + bi_b[f]], 1);
    }
}

__global__ void dinv_all(const int* __restrict__ deg, float* __restrict__ dinv, int n) {
    int i = blockIdx.x * blockDim.x + threadIdx.x;
    if (i >= n) return;
    dinv[i] = 1.0f / (sqrtf((float)deg[i]) + EPSN);
}

// ---------------- exclusive scan over the whole deg region ----------------
__global__ void scan_a(const int* __restrict__ in, int* __restrict__ out,
                       int* __restrict__ bsum, int nelem) {
    __shared__ int tsum[SCAN_TPB];
    int tid = threadIdx.x;
    int base = blockIdx.x * SCAN_ELEMS + tid * 4;
    int v0 = (base + 0 < nelem) ? in[base + 0] : 0;
    int v1 = (base + 1 < nelem) ? in[base + 1] : 0;
    int v2 = (base + 2 < nelem) ? in[base + 2] : 0;
    int v3 = (base + 3 < nelem) ? in[base + 3] : 0;
    int s = v0 + v1 + v2 + v3;
    tsum[tid] = s;
    __syncthreads();
    for (int off = 1; off < SCAN_TPB; off <<= 1) {
        int y = (tid >= off) ? tsum[tid - off] : 0;
        __syncthreads();
        tsum[tid] += y;
        __syncthreads();
    }
    int excl = tsum[tid] - s;
    if (tid == SCAN_TPB - 1) bsum[blockIdx.x] = tsum[SCAN_TPB - 1];
    if (base + 0 < nelem) out[base + 0] = excl;
    excl += v0;
    if (base + 1 < nelem) out[base + 1] = excl;
    excl += v1;
    if (base + 2 < nelem) out[base + 2] = excl;
    excl += v2;
    if (base + 3 < nelem) out[base + 3] = excl;
}

__global__ void scan_b(int* __restrict__ bsum, int nb) {   // nb <= 512, one block of 512
    __shared__ int sm[512];
    int tid = threadIdx.x;
    int v = (tid < nb) ? bsum[tid] : 0;
    sm[tid] = v;
    __syncthreads();
    for (int off = 1; off < 512; off <<= 1) {
        int y = (tid >= off) ? sm[tid - off] : 0;
        __syncthreads();
        sm[tid] += y;
        __syncthreads();
    }
    if (tid < nb) bsum[tid] = sm[tid] - v;   // exclusive
}

__global__ void scan_c(int* __restrict__ out, const int* __restrict__ bsum, int nelem) {
    int base = blockIdx.x * SCAN_ELEMS + threadIdx.x * 4;
    int add = bsum[blockIdx.x];
#pragma unroll
    for (int k = 0; k < 4; ++k)
        if (base + k < nelem) out[base + k] += add;
}

// ---------------- merged CSR build (unified cols/wts, global offsets) ----------------
__global__ void build_all(const int* __restrict__ ub_u, const int* __restrict__ ub_b,
                          const int* __restrict__ ui_u, const int* __restrict__ ui_i,
                          const int* __restrict__ bi_b, const int* __restrict__ bi_i,
                          const float* __restrict__ bi_vals,
                          int E_UB, int E_UI, int E_BI, int NU, int n1, int n2,
                          int* __restrict__ cursor, int* __restrict__ cols,
                          float* __restrict__ wts) {
    int e = blockIdx.x * blockDim.x + threadIdx.x;
    if (e < E_UB) {
        int a = ub_u[e], b = ub_b[e] + NU;
        int pa = atomicAdd(&cursor[a], 1); cols[pa] = b;
        int pb = atomicAdd(&cursor[b], 1); cols[pb] = a;
    } else if (e < E_UB + E_UI) {
        int f = e - E_UB;
        int a = ui_u[f], b = ui_i[f] + NU;           // graph-local ids
        int pa = atomicAdd(&cursor[n1 + a], 1); cols[pa] = b;
        int pb = atomicAdd(&cursor[n1 + b], 1); cols[pb] = a;
    } else if (e < E_UB + E_UI + E_BI) {
        int f = e - E_UB - E_UI;
        int pos = atomicAdd(&cursor[n1 + n2 + bi_b[f]], 1);
        cols[pos] = bi_i[f];
        wts[pos] = bi_vals[f];
    }
}

// ---------------- prep: raw16 = bf16(feats), fini16 = bf16(l2norm(feats)) ----------------
__global__ void prep_kernel(const float* __restrict__ uf, const float* __restrict__ bf,
                            const float* __restrict__ itf, int NU, int NB, int NT,
                            uint* __restrict__ raw16, uint* __restrict__ fini16) {
    int w = (blockIdx.x * blockDim.x + threadIdx.x) >> 6;
    int lane = threadIdx.x & 63;
    if (w >= NT) return;
    const float* src = (w < NU) ? uf + (size_t)w * FD
                     : (w < NU + NB) ? bf + (size_t)(w - NU) * FD
                     : itf + (size_t)(w - NU - NB) * FD;
    float2 x = ((const float2*)src)[lane];
    float ss = wave_sum(x.x * x.x + x.y * x.y);
    float inv = 1.0f / fmaxf(sqrtf(ss), 1e-12f);
    raw16[(size_t)w * FDH + lane] = packbf2(x.x, x.y);
    fini16[(size_t)w * FDH + lane] = packbf2(x.x * inv, x.y * inv);
}

// ---------------- fused gather SpMM + post + writeout ----------------
// mode 0 (layer1): fX16[w] = bf16(v);  facc[w] = raw[w] + v
// mode 1 (UB L2) : out[NU+w] / out[2NU+NB+(w-NU)] = facc[w] + v
// mode 2 (UI L2) : users: out[w] = facc[w] + v ; items: items16[w-NU] = bf16(facc[w]+v)
__global__ void spmm_fused(const int* __restrict__ rowptr, const int* __restrict__ cols,
                           const float* __restrict__ dinv,
                           const uint* __restrict__ gtab, int gAddB,
                           const uint* __restrict__ fini16, int fAddB,
                           const float* __restrict__ af, const float* __restrict__ bsrc,
                           float* __restrict__ facc, uint* __restrict__ fX16,
                           float sc, int n, int NU, int mode, int NB,
                           float* __restrict__ outp, uint* __restrict__ items16) {
    int w = (blockIdx.x * blockDim.x + threadIdx.x) >> 6;
    int lane = threadIdx.x & 63;
    if (w >= n) return;
    int s = rowptr[w], e = rowptr[w + 1];
    float dr = dinv[w];
    float ax = 0.0f, ay = 0.0f;
    int j = s;
    for (; j + 2 <= e; j += 2) {
        int c0 = cols[j], c1 = cols[j + 1];
        float w0 = dr * dinv[c0], w1 = dr * dinv[c1];
        int m0 = c0 + ((c0 >= NU) ? gAddB : 0);
        int m1 = c1 + ((c1 >= NU) ? gAddB : 0);
        uint x0 = gtab[(size_t)m0 * FDH + lane];
        uint x1 = gtab[(size_t)m1 * FDH + lane];
        float2 f0 = unpackbf2(x0), f1 = unpackbf2(x1);
        ax = fmaf(w0, f0.x, ax); ay = fmaf(w0, f0.y, ay);
        ax = fmaf(w1, f1.x, ax); ay = fmaf(w1, f1.y, ay);
    }
    if (j < e) {
        int c0 = cols[j];
        float w0 = dr * dinv[c0];
        int m0 = c0 + ((c0 >= NU) ? gAddB : 0);
        float2 f0 = unpackbf2(gtab[(size_t)m0 * FDH + lane]);
        ax = fmaf(w0, f0.x, ax); ay = fmaf(w0, f0.y, ay);
    }
    int fr = w + ((w >= NU) ? fAddB : 0);
    float2 i0 = unpackbf2(fini16[(size_t)fr * FDH + lane]);
    float vx = (ax + RCC * i0.x) * sc;
    float vy = (ay + RCC * i0.y) * sc;
    float ss = wave_sum(vx * vx + vy * vy);
    float inv = 1.0f / fmaxf(sqrtf(ss), 1e-12f);
    vx *= inv; vy *= inv;
    if (mode == 0) {
        const float* rsrc = (w < NU) ? af + (size_t)w * FD : bsrc + (size_t)(w - NU) * FD;
        float2 r = ((const float2*)rsrc)[lane];
        fX16[(size_t)w * FDH + lane] = packbf2(vx, vy);
        ((float2*)(facc + (size_t)w * FD))[lane] = make_float2(r.x + vx, r.y + vy);
    } else {
        float2 a0 = ((const float2*)(facc + (size_t)w * FD))[lane];
        float2 an = make_float2(a0.x + vx, a0.y + vy);
        if (mode == 1) {
            size_t dst = (w < NU) ? (size_t)(NU + w) : (size_t)(2 * NU + NB + (w - NU));
            ((float2*)(outp + dst * FD))[lane] = an;
        } else {
            if (w < NU) ((float2*)(outp + (size_t)w * FD))[lane] = an;
            else        items16[(size_t)(w - NU) * FDH + lane] = packbf2(an.x, an.y);
        }
    }
}

// ---------------- BI gather from bf16 items ----------------
__global__ void bi_gather(const int* __restrict__ rowptr, const int* __restrict__ cols,
                          const float* __restrict__ wts, const uint* __restrict__ items16,
                          float* __restrict__ outb, int nb) {
    int w = (blockIdx.x * blockDim.x + threadIdx.x) >> 6;
    int lane = threadIdx.x & 63;
    if (w >= nb) return;
    int s = rowptr[w], e = rowptr[w + 1];
    float ax = 0.0f, ay = 0.0f;
    int j = s;
    for (; j + 2 <= e; j += 2) {
        int c0 = cols[j], c1 = cols[j + 1];
        float w0 = wts[j], w1 = wts[j + 1];
        uint x0 = items16[(size_t)c0 * FDH + lane];
        uint x1 = items16[(size_t)c1 * FDH + lane];
        float2 f0 = unpackbf2(x0), f1 = unpackbf2(x1);
        ax = fmaf(w0, f0.x, ax); ay = fmaf(w0, f0.y, ay);
        ax = fmaf(w1, f1.x, ax); ay = fmaf(w1, f1.y, ay);
    }
    if (j < e) {
        float w0 = wts[j];
        float2 f0 = unpackbf2(items16[(size_t)cols[j] * FDH + lane]);
        ax = fmaf(w0, f0.x, ax); ay = fmaf(w0, f0.y, ay);
    }
    ((float2*)(outb + (size_t)w * FD))[lane] = make_float2(ax, ay);
}

extern "C" void kernel_launch(void* const* d_in, const int* in_sizes, int n_in,
                              void* d_out, int out_size, void* d_ws, size_t ws_size,
                              hipStream_t stream) {
    const float* users   = (const float*)d_in[0];
    const float* bundles = (const float*)d_in[1];
    const float* items   = (const float*)d_in[2];
    const float* bi_vals = (const float*)d_in[3];
    const int* ub_u = (const int*)d_in[4];
    const int* ub_b = (const int*)d_in[5];
    const int* ui_u = (const int*)d_in[6];
    const int* ui_i = (const int*)d_in[7];
    const int* bi_b = (const int*)d_in[8];
    const int* bi_i = (const int*)d_in[9];

    const int NU = in_sizes[0] / FD;
    const int NB = in_sizes[1] / FD;
    const int NI = in_sizes[2] / FD;
    const int E_BI = in_sizes[3];
    const int E_UB = in_sizes[4];
    const int E_UI = in_sizes[6];
    float* out = (float*)d_out;

    const int n1 = NU + NB, n2 = NU + NI;
    const int NT = NU + NB + NI;
    const int NMAX = (n1 > n2) ? n1 : n2;
    const int NN = n1 + n2 + NB;                 // total CSR rows
    const long TOT = 2L * E_UB + 2L * E_UI + E_BI;  // total CSR entries
    const int ETOT = E_UB + E_UI + E_BI;

    // ---- workspace layout ----
    float* facc   = (float*)d_ws;                          // NMAX*FD f32
    uint* raw16   = (uint*)(facc + (size_t)NMAX * FD);     // NT*FDH
    uint* fini16  = raw16 + (size_t)NT * FDH;              // NT*FDH
    uint* fX16    = fini16 + (size_t)NT * FDH;             // NMAX*FDH
    uint* items16 = fX16 + (size_t)NMAX * FDH;             // NI*FDH
    float* dinv   = (float*)(items16 + (size_t)NI * FDH);  // n1+n2
    float* wts    = dinv + (n1 + n2);                      // TOT
    int* deg      = (int*)(wts + TOT);                     // NN+1
    int* scanb    = deg + (NN + 1);                        // NN+1
    int* cursor   = scanb + (NN + 1);                      // NN
    int* bsum     = cursor + NN;                           // 512
    int* cols     = bsum + 512;                            // TOT

    dim3 blk(256);
    auto rows_grid = [](int n) { return dim3((unsigned)((n + 3) / 4)); };
    auto thr_grid  = [](int n) { return dim3((unsigned)((n + 255) / 256)); };

    // ---- merged CSR build ----
    hipMemsetAsync(deg, 0, (size_t)(NN + 1) * 4, stream);
    deg_all<<<thr_grid(ETOT), blk, 0, stream>>>(ub_u, ub_b, ui_u, ui_i, bi_b,
        E_UB, E_UI, E_BI, NU, n1, n2, deg);
    dinv_all<<<thr_grid(n1 + n2), blk, 0, stream>>>(deg, dinv, n1 + n2);
    {
        int nelem = NN + 1;
        int nblk = (nelem + SCAN_ELEMS - 1) / SCAN_ELEMS;
        scan_a<<<dim3((unsigned)nblk), dim3(SCAN_TPB), 0, stream>>>(deg, scanb, bsum, nelem);
        scan_b<<<dim3(1), dim3(512), 0, stream>>>(bsum, nblk);
        scan_c<<<dim3((unsigned)nblk), dim3(SCAN_TPB), 0, stream>>>(scanb, bsum, nelem);
    }
    hipMemcpyAsync(cursor, scanb, (size_t)NN * 4, hipMemcpyDeviceToDevice, stream);
    build_all<<<thr_grid(ETOT), blk, 0, stream>>>(ub_u, ub_b, ui_u, ui_i, bi_b, bi_i, bi_vals,
        E_UB, E_UI, E_BI, NU, n1, n2, cursor, cols, wts);

    // ---- features prep ----
    prep_kernel<<<rows_grid(NT), blk, 0, stream>>>(users, bundles, items, NU, NB, NT,
                                                   raw16, fini16);

    // ---- UB propagation ----
    spmm_fused<<<rows_grid(n1), blk, 0, stream>>>(scanb, cols, dinv,
        raw16, 0, fini16, 0, users, bundles, facc, fX16, 0.5f, n1, NU, 0, NB, out, items16);
    spmm_fused<<<rows_grid(n1), blk, 0, stream>>>(scanb, cols, dinv,
        fX16, 0, fini16, 0, users, bundles, facc, fX16, 1.0f / 3.0f, n1, NU, 1, NB, out, items16);

    // ---- UI propagation ----
    spmm_fused<<<rows_grid(n2), blk, 0, stream>>>(scanb + n1, cols, dinv + n1,
        raw16, NB, fini16, NB, users, items, facc, fX16, 0.5f, n2, NU, 0, NB, out, items16);
    spmm_fused<<<rows_grid(n2), blk, 0, stream>>>(scanb + n1, cols, dinv + n1,
        fX16, 0, fini16, NB, users, items, facc, fX16, 1.0f / 3.0f, n2, NU, 2, NB, out, items16);

    // ---- BI aggregation ----
    bi_gather<<<rows_grid(NB), blk, 0, stream>>>(scanb + n1 + n2, cols, wts, items16,
        out + (size_t)2 * NU * FD, NB);
}

// Round 4
// 800.874 us; speedup vs baseline: 4.5299x; 1.1649x over previous
//
#include <hip/hip_runtime.h>

#define FD   128        // feature dim (floats)
#define FDH  64         // uints per row when stored as bf16x2
#define EPSN 1e-8f
#define RCC  0.5f
#define SCAN_TPB 256
#define SCAN_ELEMS 1024

typedef unsigned int uint;

__device__ __forceinline__ float wave_sum(float x) {
#pragma unroll
    for (int off = 32; off > 0; off >>= 1) x += __shfl_xor(x, off);
    return x;
}

__device__ __forceinline__ uint packbf2(float a, float b) {
    uint ua = __float_as_uint(a); ua += 0x7fffu + ((ua >> 16) & 1u);
    uint ub = __float_as_uint(b); ub += 0x7fffu + ((ub >> 16) & 1u);
    return (ua >> 16) | (ub & 0xffff0000u);
}
__device__ __forceinline__ float2 unpackbf2(uint v) {
    return make_float2(__uint_as_float(v << 16), __uint_as_float(v & 0xffff0000u));
}

// ---------------- Pass A: linked-list insert (1 atomicExch per insertion) + fused prep ----
// slot layout: UB edge e -> slots 2e,2e+1 ; UI edge f -> 2E_UB+2f,+1 ; BI edge g -> 2E_UB+2E_UI+g
__global__ void passA(const int* __restrict__ ub_u, const int* __restrict__ ub_b,
                      const int* __restrict__ ui_u, const int* __restrict__ ui_i,
                      const int* __restrict__ bi_b, const int* __restrict__ bi_i,
                      const float* __restrict__ uf, const float* __restrict__ bf,
                      const float* __restrict__ itf,
                      int E_UB, int E_UI, int E_BI, int NU, int NB, int n1, int n2, int NT,
                      int nblk_edges,
                      int* __restrict__ head, int2* __restrict__ pairLL,
                      uint* __restrict__ raw16, uint* __restrict__ fini16) {
    if ((int)blockIdx.x < nblk_edges) {
        int e = blockIdx.x * blockDim.x + threadIdx.x;
        if (e < E_UB) {
            int a = ub_u[e], b = ub_b[e] + NU;
            int s0 = 2 * e;
            int p0 = atomicExch(&head[a], s0);
            int p1 = atomicExch(&head[b], s0 + 1);
            ((int4*)pairLL)[e] = make_int4(p0, b, p1, a);
        } else if (e < E_UB + E_UI) {
            int f = e - E_UB;
            int a = ui_u[f], bl = ui_i[f] + NU;     // graph-local col ids
            int s0 = 2 * E_UB + 2 * f;
            int p0 = atomicExch(&head[n1 + a], s0);
            int p1 = atomicExch(&head[n1 + bl], s0 + 1);
            ((int4*)pairLL)[E_UB + f] = make_int4(p0, bl, p1, a);
        } else if (e < E_UB + E_UI + E_BI) {
            int g = e - E_UB - E_UI;
            int s = 2 * E_UB + 2 * E_UI + g;
            int p = atomicExch(&head[n1 + n2 + bi_b[g]], s);
            pairLL[s] = make_int2(p, bi_i[g]);
        }
    } else {
        int w = (((int)blockIdx.x - nblk_edges) * blockDim.x + threadIdx.x) >> 6;
        int lane = threadIdx.x & 63;
        if (w >= NT) return;
        const float* src = (w < NU) ? uf + (size_t)w * FD
                         : (w < NU + NB) ? bf + (size_t)(w - NU) * FD
                         : itf + (size_t)(w - NU - NB) * FD;
        float2 x = ((const float2*)src)[lane];
        float ss = wave_sum(x.x * x.x + x.y * x.y);
        float inv = 1.0f / fmaxf(sqrtf(ss), 1e-12f);
        raw16[(size_t)w * FDH + lane] = packbf2(x.x, x.y);
        fini16[(size_t)w * FDH + lane] = packbf2(x.x * inv, x.y * inv);
    }
}

// ---------------- Pass B: chain length -> deg (+dinv) ----------------
__global__ void passB(const int* __restrict__ head, const int2* __restrict__ pairLL,
                      int NN, int n12, int* __restrict__ deg, float* __restrict__ dinv) {
    int r = blockIdx.x * blockDim.x + threadIdx.x;
    if (r >= NN) { if (r == NN) deg[NN] = 0; return; }
    int c = 0;
    int s = head[r];
    while (s >= 0) { c++; s = pairLL[s].x; }
    deg[r] = c;
    if (r < n12) dinv[r] = 1.0f / (sqrtf((float)c) + EPSN);
}

// ---------------- exclusive scan ----------------
__global__ void scan_a(const int* __restrict__ in, int* __restrict__ out,
                       int* __restrict__ bsum, int nelem) {
    __shared__ int tsum[SCAN_TPB];
    int tid = threadIdx.x;
    int base = blockIdx.x * SCAN_ELEMS + tid * 4;
    int v0 = (base + 0 < nelem) ? in[base + 0] : 0;
    int v1 = (base + 1 < nelem) ? in[base + 1] : 0;
    int v2 = (base + 2 < nelem) ? in[base + 2] : 0;
    int v3 = (base + 3 < nelem) ? in[base + 3] : 0;
    int s = v0 + v1 + v2 + v3;
    tsum[tid] = s;
    __syncthreads();
    for (int off = 1; off < SCAN_TPB; off <<= 1) {
        int y = (tid >= off) ? tsum[tid - off] : 0;
        __syncthreads();
        tsum[tid] += y;
        __syncthreads();
    }
    int excl = tsum[tid] - s;
    if (tid == SCAN_TPB - 1) bsum[blockIdx.x] = tsum[SCAN_TPB - 1];
    if (base + 0 < nelem) out[base + 0] = excl;
    excl += v0;
    if (base + 1 < nelem) out[base + 1] = excl;
    excl += v1;
    if (base + 2 < nelem) out[base + 2] = excl;
    excl += v2;
    if (base + 3 < nelem) out[base + 3] = excl;
}

__global__ void scan_b(int* __restrict__ bsum, int nb) {   // nb <= 512
    __shared__ int sm[512];
    int tid = threadIdx.x;
    int v = (tid < nb) ? bsum[tid] : 0;
    sm[tid] = v;
    __syncthreads();
    for (int off = 1; off < 512; off <<= 1) {
        int y = (tid >= off) ? sm[tid - off] : 0;
        __syncthreads();
        sm[tid] += y;
        __syncthreads();
    }
    if (tid < nb) bsum[tid] = sm[tid] - v;
}

__global__ void scan_c(int* __restrict__ out, const int* __restrict__ bsum, int nelem) {
    int base = blockIdx.x * SCAN_ELEMS + threadIdx.x * 4;
    int add = bsum[blockIdx.x];
#pragma unroll
    for (int k = 0; k < 4; ++k)
        if (base + k < nelem) out[base + k] += add;
}

// ---------------- Pass C: flatten chains to CSR ----------------
__global__ void passC(const int* __restrict__ head, const int2* __restrict__ pairLL,
                      const int* __restrict__ rowptr, const float* __restrict__ bi_vals,
                      int NN, int n12, int S1,
                      int* __restrict__ cols, float* __restrict__ wts) {
    int r = blockIdx.x * blockDim.x + threadIdx.x;
    if (r >= NN) return;
    int pos = rowptr[r];
    int s = head[r];
    if (r < n12) {
        while (s >= 0) { int2 p = pairLL[s]; cols[pos++] = p.y; s = p.x; }
    } else {
        while (s >= 0) {
            int2 p = pairLL[s];
            cols[pos] = p.y;
            wts[pos - S1] = bi_vals[s - S1];
            pos++; s = p.x;
        }
    }
}

// ---------------- fused gather SpMM + post + writeout ----------------
// mode 0 (layer1): fX16[w] = bf16(v);  facc[w] = raw[w] + v
// mode 1 (UB L2) : out[NU+w] / out[2NU+NB+(w-NU)] = facc[w] + v
// mode 2 (UI L2) : users: out[w] = facc[w] + v ; items: items16[w-NU] = bf16(facc[w]+v)
__global__ void spmm_fused(const int* __restrict__ rowptr, const int* __restrict__ cols,
                           const float* __restrict__ dinv,
                           const uint* __restrict__ gtab, int gAddB,
                           const uint* __restrict__ fini16, int fAddB,
                           const float* __restrict__ af, const float* __restrict__ bsrc,
                           float* __restrict__ facc, uint* __restrict__ fX16,
                           float sc, int n, int NU, int mode, int NB,
                           float* __restrict__ outp, uint* __restrict__ items16) {
    int w = (blockIdx.x * blockDim.x + threadIdx.x) >> 6;
    int lane = threadIdx.x & 63;
    if (w >= n) return;
    int s = rowptr[w], e = rowptr[w + 1];
    float dr = dinv[w];
    float ax = 0.0f, ay = 0.0f;
    int j = s;
    for (; j + 4 <= e; j += 4) {
        int c0 = cols[j], c1 = cols[j + 1], c2 = cols[j + 2], c3 = cols[j + 3];
        float w0 = dr * dinv[c0], w1 = dr * dinv[c1];
        float w2 = dr * dinv[c2], w3 = dr * dinv[c3];
        int m0 = c0 + ((c0 >= NU) ? gAddB : 0);
        int m1 = c1 + ((c1 >= NU) ? gAddB : 0);
        int m2 = c2 + ((c2 >= NU) ? gAddB : 0);
        int m3 = c3 + ((c3 >= NU) ? gAddB : 0);
        uint x0 = gtab[(size_t)m0 * FDH + lane];
        uint x1 = gtab[(size_t)m1 * FDH + lane];
        uint x2 = gtab[(size_t)m2 * FDH + lane];
        uint x3 = gtab[(size_t)m3 * FDH + lane];
        float2 f0 = unpackbf2(x0), f1 = unpackbf2(x1);
        float2 f2 = unpackbf2(x2), f3 = unpackbf2(x3);
        ax = fmaf(w0, f0.x, ax); ay = fmaf(w0, f0.y, ay);
        ax = fmaf(w1, f1.x, ax); ay = fmaf(w1, f1.y, ay);
        ax = fmaf(w2, f2.x, ax); ay = fmaf(w2, f2.y, ay);
        ax = fmaf(w3, f3.x, ax); ay = fmaf(w3, f3.y, ay);
    }
    for (; j < e; ++j) {
        int c0 = cols[j];
        float w0 = dr * dinv[c0];
        int m0 = c0 + ((c0 >= NU) ? gAddB : 0);
        float2 f0 = unpackbf2(gtab[(size_t)m0 * FDH + lane]);
        ax = fmaf(w0, f0.x, ax); ay = fmaf(w0, f0.y, ay);
    }
    int fr = w + ((w >= NU) ? fAddB : 0);
    float2 i0 = unpackbf2(fini16[(size_t)fr * FDH + lane]);
    float vx = (ax + RCC * i0.x) * sc;
    float vy = (ay + RCC * i0.y) * sc;
    float ss = wave_sum(vx * vx + vy * vy);
    float inv = 1.0f / fmaxf(sqrtf(ss), 1e-12f);
    vx *= inv; vy *= inv;
    if (mode == 0) {
        const float* rsrc = (w < NU) ? af + (size_t)w * FD : bsrc + (size_t)(w - NU) * FD;
        float2 r = ((const float2*)rsrc)[lane];
        fX16[(size_t)w * FDH + lane] = packbf2(vx, vy);
        ((float2*)(facc + (size_t)w * FD))[lane] = make_float2(r.x + vx, r.y + vy);
    } else {
        float2 a0 = ((const float2*)(facc + (size_t)w * FD))[lane];
        float2 an = make_float2(a0.x + vx, a0.y + vy);
        if (mode == 1) {
            size_t dst = (w < NU) ? (size_t)(NU + w) : (size_t)(2 * NU + NB + (w - NU));
            ((float2*)(outp + dst * FD))[lane] = an;
        } else {
            if (w < NU) ((float2*)(outp + (size_t)w * FD))[lane] = an;
            else        items16[(size_t)(w - NU) * FDH + lane] = packbf2(an.x, an.y);
        }
    }
}

// ---------------- BI gather from bf16 items ----------------
__global__ void bi_gather(const int* __restrict__ rowptr, const int* __restrict__ cols,
                          const float* __restrict__ wts, int S1,
                          const uint* __restrict__ items16,
                          float* __restrict__ outb, int nb) {
    int w = (blockIdx.x * blockDim.x + threadIdx.x) >> 6;
    int lane = threadIdx.x & 63;
    if (w >= nb) return;
    int s = rowptr[w], e = rowptr[w + 1];
    float ax = 0.0f, ay = 0.0f;
    int j = s;
    for (; j + 4 <= e; j += 4) {
        int c0 = cols[j], c1 = cols[j + 1], c2 = cols[j + 2], c3 = cols[j + 3];
        float w0 = wts[j - S1], w1 = wts[j + 1 - S1];
        float w2 = wts[j + 2 - S1], w3 = wts[j + 3 - S1];
        uint x0 = items16[(size_t)c0 * FDH + lane];
        uint x1 = items16[(size_t)c1 * FDH + lane];
        uint x2 = items16[(size_t)c2 * FDH + lane];
        uint x3 = items16[(size_t)c3 * FDH + lane];
        float2 f0 = unpackbf2(x0), f1 = unpackbf2(x1);
        float2 f2 = unpackbf2(x2), f3 = unpackbf2(x3);
        ax = fmaf(w0, f0.x, ax); ay = fmaf(w0, f0.y, ay);
        ax = fmaf(w1, f1.x, ax); ay = fmaf(w1, f1.y, ay);
        ax = fmaf(w2, f2.x, ax); ay = fmaf(w2, f2.y, ay);
        ax = fmaf(w3, f3.x, ax); ay = fmaf(w3, f3.y, ay);
    }
    for (; j < e; ++j) {
        float w0 = wts[j - S1];
        float2 f0 = unpackbf2(items16[(size_t)cols[j] * FDH + lane]);
        ax = fmaf(w0, f0.x, ax); ay = fmaf(w0, f0.y, ay);
    }
    ((float2*)(outb + (size_t)w * FD))[lane] = make_float2(ax, ay);
}

extern "C" void kernel_launch(void* const* d_in, const int* in_sizes, int n_in,
                              void* d_out, int out_size, void* d_ws, size_t ws_size,
                              hipStream_t stream) {
    const float* users   = (const float*)d_in[0];
    const float* bundles = (const float*)d_in[1];
    const float* items   = (const float*)d_in[2];
    const float* bi_vals = (const float*)d_in[3];
    const int* ub_u = (const int*)d_in[4];
    const int* ub_b = (const int*)d_in[5];
    const int* ui_u = (const int*)d_in[6];
    const int* ui_i = (const int*)d_in[7];
    const int* bi_b = (const int*)d_in[8];
    const int* bi_i = (const int*)d_in[9];

    const int NU = in_sizes[0] / FD;
    const int NB = in_sizes[1] / FD;
    const int NI = in_sizes[2] / FD;
    const int E_BI = in_sizes[3];
    const int E_UB = in_sizes[4];
    const int E_UI = in_sizes[6];
    float* out = (float*)d_out;

    const int n1 = NU + NB, n2 = NU + NI;
    const int NT = NU + NB + NI;
    const int NMAX = (n1 > n2) ? n1 : n2;
    const int NN = n1 + n2 + NB;                    // total CSR rows
    const int S1 = 2 * E_UB + 2 * E_UI;             // first BI slot / BI rowptr base
    const int TOT = S1 + E_BI;                      // total CSR entries
    const int ETOT = E_UB + E_UI + E_BI;

    // ---- workspace layout ----
    float* facc   = (float*)d_ws;                          // NMAX*FD f32
    uint* raw16   = (uint*)(facc + (size_t)NMAX * FD);     // NT*FDH
    uint* fini16  = raw16 + (size_t)NT * FDH;              // NT*FDH
    uint* fX16    = fini16 + (size_t)NT * FDH;             // NMAX*FDH
    uint* items16 = fX16 + (size_t)NMAX * FDH;             // NI*FDH
    float* dinv   = (float*)(items16 + (size_t)NI * FDH);  // n1+n2
    float* wts    = dinv + (n1 + n2);                      // E_BI
    int* deg      = (int*)(wts + E_BI);                    // NN+1
    int* rowptr   = deg + (NN + 1);                        // NN+1
    int* head     = rowptr + (NN + 1);                     // NN
    int* bsum     = head + NN;                             // 512
    int* cols     = bsum + 512;                            // TOT
    int2* pairLL  = (int2*)((((size_t)(cols + TOT)) + 15) & ~(size_t)15);  // TOT int2

    dim3 blk(256);
    auto rows_grid = [](int n) { return dim3((unsigned)((n + 3) / 4)); };
    auto thr_grid  = [](int n) { return dim3((unsigned)((n + 255) / 256)); };

    // ---- linked-list CSR build (one atomic pass) + fused feature prep ----
    hipMemsetAsync(head, 0xFF, (size_t)NN * 4, stream);    // head = -1
    int nblk_edges = (ETOT + 255) / 256;
    int nblk_prep  = (NT + 3) / 4;
    passA<<<dim3((unsigned)(nblk_edges + nblk_prep)), blk, 0, stream>>>(
        ub_u, ub_b, ui_u, ui_i, bi_b, bi_i, users, bundles, items,
        E_UB, E_UI, E_BI, NU, NB, n1, n2, NT, nblk_edges,
        head, pairLL, raw16, fini16);
    passB<<<thr_grid(NN + 1), blk, 0, stream>>>(head, pairLL, NN, n1 + n2, deg, dinv);
    {
        int nelem = NN + 1;
        int nblk = (nelem + SCAN_ELEMS - 1) / SCAN_ELEMS;
        scan_a<<<dim3((unsigned)nblk), dim3(SCAN_TPB), 0, stream>>>(deg, rowptr, bsum, nelem);
        scan_b<<<dim3(1), dim3(512), 0, stream>>>(bsum, nblk);
        scan_c<<<dim3((unsigned)nblk), dim3(SCAN_TPB), 0, stream>>>(rowptr, bsum, nelem);
    }
    passC<<<thr_grid(NN), blk, 0, stream>>>(head, pairLL, rowptr, bi_vals,
                                            NN, n1 + n2, S1, cols, wts);

    // ---- UB propagation ----
    spmm_fused<<<rows_grid(n1), blk, 0, stream>>>(rowptr, cols, dinv,
        raw16, 0, fini16, 0, users, bundles, facc, fX16, 0.5f, n1, NU, 0, NB, out, items16);
    spmm_fused<<<rows_grid(n1), blk, 0, stream>>>(rowptr, cols, dinv,
        fX16, 0, fini16, 0, users, bundles, facc, fX16, 1.0f / 3.0f, n1, NU, 1, NB, out, items16);

    // ---- UI propagation ----
    spmm_fused<<<rows_grid(n2), blk, 0, stream>>>(rowptr + n1, cols, dinv + n1,
        raw16, NB, fini16, NB, users, items, facc, fX16, 0.5f, n2, NU, 0, NB, out, items16);
    spmm_fused<<<rows_grid(n2), blk, 0, stream>>>(rowptr + n1, cols, dinv + n1,
        fX16, 0, fini16, NB, users, items, facc, fX16, 1.0f / 3.0f, n2, NU, 2, NB, out, items16);

    // ---- BI aggregation ----
    bi_gather<<<rows_grid(NB), blk, 0, stream>>>(rowptr + n1 + n2, cols, wts, S1, items16,
        out + (size_t)2 * NU * FD, NB);
}

// Round 8
// 721.750 us; speedup vs baseline: 5.0265x; 1.1096x over previous
//
#include <hip/hip_runtime.h>

#define FD   128        // feature dim (floats)
#define FDH  64         // uints per row when stored as bf16x2
#define EPSN 1e-8f
#define RCC  0.5f
#define SCAN_TPB 256
#define SCAN_ELEMS 1024

typedef unsigned int uint;

__device__ __forceinline__ float wave_sum(float x) {
#pragma unroll
    for (int off = 32; off > 0; off >>= 1) x += __shfl_xor(x, off);
    return x;
}

__device__ __forceinline__ uint packbf2(float a, float b) {
    uint ua = __float_as_uint(a); ua += 0x7fffu + ((ua >> 16) & 1u);
    uint ub = __float_as_uint(b); ub += 0x7fffu + ((ub >> 16) & 1u);
    return (ua >> 16) | (ub & 0xffff0000u);
}
__device__ __forceinline__ float2 unpackbf2(uint v) {
    return make_float2(__uint_as_float(v << 16), __uint_as_float(v & 0xffff0000u));
}

// ---------------- Pass A: linked-list insert (1 atomicExch per insertion) + fused prep ----
// slot layout: UB edge e -> slots 2e,2e+1 ; UI edge f -> 2E_UB+2f,+1 ; BI edge g -> 2E_UB+2E_UI+g
__global__ void passA(const int* __restrict__ ub_u, const int* __restrict__ ub_b,
                      const int* __restrict__ ui_u, const int* __restrict__ ui_i,
                      const int* __restrict__ bi_b, const int* __restrict__ bi_i,
                      const float* __restrict__ uf, const float* __restrict__ bf,
                      const float* __restrict__ itf,
                      int E_UB, int E_UI, int E_BI, int NU, int NB, int n1, int n2, int NT,
                      int nblk_edges,
                      int* __restrict__ head, int2* __restrict__ pairLL,
                      uint* __restrict__ fini16, float* __restrict__ normf) {
    if ((int)blockIdx.x < nblk_edges) {
        int e = blockIdx.x * blockDim.x + threadIdx.x;
        if (e < E_UB) {
            int a = ub_u[e], b = ub_b[e] + NU;
            int s0 = 2 * e;
            int p0 = atomicExch(&head[a], s0);
            int p1 = atomicExch(&head[b], s0 + 1);
            ((int4*)pairLL)[e] = make_int4(p0, b, p1, a);
        } else if (e < E_UB + E_UI) {
            int f = e - E_UB;
            int a = ui_u[f], bl = ui_i[f] + NU;     // graph-local col ids
            int s0 = 2 * E_UB + 2 * f;
            int p0 = atomicExch(&head[n1 + a], s0);
            int p1 = atomicExch(&head[n1 + bl], s0 + 1);
            ((int4*)pairLL)[E_UB + f] = make_int4(p0, bl, p1, a);
        } else if (e < E_UB + E_UI + E_BI) {
            int g = e - E_UB - E_UI;
            int s = 2 * E_UB + 2 * E_UI + g;
            int p = atomicExch(&head[n1 + n2 + bi_b[g]], s);
            pairLL[s] = make_int2(p, bi_i[g]);
        }
    } else {
        int w = (((int)blockIdx.x - nblk_edges) * blockDim.x + threadIdx.x) >> 6;
        int lane = threadIdx.x & 63;
        if (w >= NT) return;
        const float* src = (w < NU) ? uf + (size_t)w * FD
                         : (w < NU + NB) ? bf + (size_t)(w - NU) * FD
                         : itf + (size_t)(w - NU - NB) * FD;
        float2 x = ((const float2*)src)[lane];
        float ss = wave_sum(x.x * x.x + x.y * x.y);
        float nrm = sqrtf(ss);
        float inv = 1.0f / fmaxf(nrm, 1e-12f);
        fini16[(size_t)w * FDH + lane] = packbf2(x.x * inv, x.y * inv);
        if (lane == 0) normf[w] = nrm;
    }
}

// ---------------- Pass B: chain length -> deg, dinv, scaled1 ----------------
__global__ void passB(const int* __restrict__ head, const int2* __restrict__ pairLL,
                      int NN, int n1, int n2, int NU, int NB,
                      const float* __restrict__ normf,
                      int* __restrict__ deg, float* __restrict__ dinv,
                      float* __restrict__ scaled1) {
    int r = blockIdx.x * blockDim.x + threadIdx.x;
    if (r > NN) return;
    if (r == NN) { deg[NN] = 0; return; }
    int c = 0;
    int s = head[r];
    while (s >= 0) { c++; s = pairLL[s].x; }
    deg[r] = c;
    int n12 = n1 + n2;
    if (r < n12) {
        float dv = 1.0f / (sqrtf((float)c) + EPSN);
        dinv[r] = dv;
        int node = (r < n1) ? r : ((r - n1 < NU) ? (r - n1) : (r - n1 + NB));
        scaled1[r] = dv * normf[node];
    }
}

// ---------------- exclusive scan ----------------
__global__ void scan_a(const int* __restrict__ in, int* __restrict__ out,
                       int* __restrict__ bsum, int nelem) {
    __shared__ int tsum[SCAN_TPB];
    int tid = threadIdx.x;
    int base = blockIdx.x * SCAN_ELEMS + tid * 4;
    int v0 = (base + 0 < nelem) ? in[base + 0] : 0;
    int v1 = (base + 1 < nelem) ? in[base + 1] : 0;
    int v2 = (base + 2 < nelem) ? in[base + 2] : 0;
    int v3 = (base + 3 < nelem) ? in[base + 3] : 0;
    int s = v0 + v1 + v2 + v3;
    tsum[tid] = s;
    __syncthreads();
    for (int off = 1; off < SCAN_TPB; off <<= 1) {
        int y = (tid >= off) ? tsum[tid - off] : 0;
        __syncthreads();
        tsum[tid] += y;
        __syncthreads();
    }
    int excl = tsum[tid] - s;
    if (tid == SCAN_TPB - 1) bsum[blockIdx.x] = tsum[SCAN_TPB - 1];
    if (base + 0 < nelem) out[base + 0] = excl;
    excl += v0;
    if (base + 1 < nelem) out[base + 1] = excl;
    excl += v1;
    if (base + 2 < nelem) out[base + 2] = excl;
    excl += v2;
    if (base + 3 < nelem) out[base + 3] = excl;
}

__global__ void scan_b(int* __restrict__ bsum, int nb) {   // nb <= 512
    __shared__ int sm[512];
    int tid = threadIdx.x;
    int v = (tid < nb) ? bsum[tid] : 0;
    sm[tid] = v;
    __syncthreads();
    for (int off = 1; off < 512; off <<= 1) {
        int y = (tid >= off) ? sm[tid - off] : 0;
        __syncthreads();
        sm[tid] += y;
        __syncthreads();
    }
    if (tid < nb) bsum[tid] = sm[tid] - v;
}

__global__ void scan_c(int* __restrict__ out, const int* __restrict__ bsum, int nelem) {
    int base = blockIdx.x * SCAN_ELEMS + threadIdx.x * 4;
    int add = bsum[blockIdx.x];
#pragma unroll
    for (int k = 0; k < 4; ++k)
        if (base + k < nelem) out[base + k] += add;
}

// ---------------- Pass C: flatten chains to CSR ----------------
__global__ void passC(const int* __restrict__ head, const int2* __restrict__ pairLL,
                      const int* __restrict__ rowptr, const float* __restrict__ bi_vals,
                      int NN, int n12, int S1,
                      int* __restrict__ cols, float* __restrict__ wts) {
    int r = blockIdx.x * blockDim.x + threadIdx.x;
    if (r >= NN) return;
    int pos = rowptr[r];
    int s = head[r];
    if (r < n12) {
        while (s >= 0) { int2 p = pairLL[s]; cols[pos++] = p.y; s = p.x; }
    } else {
        while (s >= 0) {
            int2 p = pairLL[s];
            cols[pos] = p.y;
            wts[pos - S1] = bi_vals[s - S1];
            pos++; s = p.x;
        }
    }
}

// ---------------- Layer 1 (both graphs): gather fini16 with scaled1 col weights ----------
// v = (dr*sum + RCC*i0)*0.5, l2norm; facc16 = bf16(i0*norm + v); fX16 = bf16(v*dr)
__global__ void spmm_L1(const int* __restrict__ rowptr, const int* __restrict__ cols,
                        const float* __restrict__ dinv, const float* __restrict__ scaled1,
                        const float* __restrict__ normf, const uint* __restrict__ fini16,
                        uint* __restrict__ facc16, uint* __restrict__ fX16,
                        int n1, int NU, int NB, int n12) {
    int w = (blockIdx.x * blockDim.x + threadIdx.x) >> 6;
    int lane = threadIdx.x & 63;
    if (w >= n12) return;
    int s = rowptr[w], e = rowptr[w + 1];
    bool ui = (w >= n1);
    int sB = ui ? n1 : 0;
    int nAdd = ui ? NB : 0;
    int node = ui ? ((w - n1 < NU) ? (w - n1) : (w - n1 + NB)) : w;
    float dr = dinv[w];
    float ax = 0.0f, ay = 0.0f;
    int j = s;
    for (; j + 4 <= e; j += 4) {
        int c0 = cols[j], c1 = cols[j + 1], c2 = cols[j + 2], c3 = cols[j + 3];
        float w0 = scaled1[sB + c0], w1 = scaled1[sB + c1];
        float w2 = scaled1[sB + c2], w3 = scaled1[sB + c3];
        int m0 = c0 + ((c0 >= NU) ? nAdd : 0);
        int m1 = c1 + ((c1 >= NU) ? nAdd : 0);
        int m2 = c2 + ((c2 >= NU) ? nAdd : 0);
        int m3 = c3 + ((c3 >= NU) ? nAdd : 0);
        uint x0 = fini16[(size_t)m0 * FDH + lane];
        uint x1 = fini16[(size_t)m1 * FDH + lane];
        uint x2 = fini16[(size_t)m2 * FDH + lane];
        uint x3 = fini16[(size_t)m3 * FDH + lane];
        float2 f0 = unpackbf2(x0), f1 = unpackbf2(x1);
        float2 f2 = unpackbf2(x2), f3 = unpackbf2(x3);
        ax = fmaf(w0, f0.x, ax); ay = fmaf(w0, f0.y, ay);
        ax = fmaf(w1, f1.x, ax); ay = fmaf(w1, f1.y, ay);
        ax = fmaf(w2, f2.x, ax); ay = fmaf(w2, f2.y, ay);
        ax = fmaf(w3, f3.x, ax); ay = fmaf(w3, f3.y, ay);
    }
    for (; j < e; ++j) {
        int c0 = cols[j];
        float w0 = scaled1[sB + c0];
        int m0 = c0 + ((c0 >= NU) ? nAdd : 0);
        float2 f0 = unpackbf2(fini16[(size_t)m0 * FDH + lane]);
        ax = fmaf(w0, f0.x, ax); ay = fmaf(w0, f0.y, ay);
    }
    float2 i0 = unpackbf2(fini16[(size_t)node * FDH + lane]);
    float vx = (dr * ax + RCC * i0.x) * 0.5f;
    float vy = (dr * ay + RCC * i0.y) * 0.5f;
    float ss = wave_sum(vx * vx + vy * vy);
    float inv = 1.0f / fmaxf(sqrtf(ss), 1e-12f);
    vx *= inv; vy *= inv;
    float nr = normf[node];
    facc16[(size_t)w * FDH + lane] = packbf2(fmaf(i0.x, nr, vx), fmaf(i0.y, nr, vy));
    fX16[(size_t)w * FDH + lane] = packbf2(vx * dr, vy * dr);
}

// ---------------- Layer 2 (both graphs): pure gather from pre-scaled fX16 --------------
// v2 = (dr*sum + RCC*i0)/3, l2norm; an = facc16 + v2 -> out / items16
__global__ void spmm_L2(const int* __restrict__ rowptr, const int* __restrict__ cols,
                        const float* __restrict__ dinv, const uint* __restrict__ fini16,
                        const uint* __restrict__ facc16, const uint* __restrict__ fX16,
                        uint* __restrict__ items16, float* __restrict__ outp,
                        int n1, int NU, int NB, int n12) {
    int w = (blockIdx.x * blockDim.x + threadIdx.x) >> 6;
    int lane = threadIdx.x & 63;
    if (w >= n12) return;
    int s = rowptr[w], e = rowptr[w + 1];
    bool ui = (w >= n1);
    int sB = ui ? n1 : 0;
    int node = ui ? ((w - n1 < NU) ? (w - n1) : (w - n1 + NB)) : w;
    float dr = dinv[w];
    float ax = 0.0f, ay = 0.0f;
    int j = s;
    for (; j + 4 <= e; j += 4) {
        int c0 = cols[j], c1 = cols[j + 1], c2 = cols[j + 2], c3 = cols[j + 3];
        uint x0 = fX16[(size_t)(sB + c0) * FDH + lane];
        uint x1 = fX16[(size_t)(sB + c1) * FDH + lane];
        uint x2 = fX16[(size_t)(sB + c2) * FDH + lane];
        uint x3 = fX16[(size_t)(sB + c3) * FDH + lane];
        float2 f0 = unpackbf2(x0), f1 = unpackbf2(x1);
        float2 f2 = unpackbf2(x2), f3 = unpackbf2(x3);
        ax += f0.x + f1.x + f2.x + f3.x;
        ay += f0.y + f1.y + f2.y + f3.y;
    }
    for (; j < e; ++j) {
        float2 f0 = unpackbf2(fX16[(size_t)(sB + cols[j]) * FDH + lane]);
        ax += f0.x; ay += f0.y;
    }
    float2 i0 = unpackbf2(fini16[(size_t)node * FDH + lane]);
    float vx = (dr * ax + RCC * i0.x) * (1.0f / 3.0f);
    float vy = (dr * ay + RCC * i0.y) * (1.0f / 3.0f);
    float ss = wave_sum(vx * vx + vy * vy);
    float inv = 1.0f / fmaxf(sqrtf(ss), 1e-12f);
    vx *= inv; vy *= inv;
    float2 a0 = unpackbf2(facc16[(size_t)w * FDH + lane]);
    float anx = a0.x + vx, any = a0.y + vy;
    if (!ui) {
        size_t dst = (w < NU) ? (size_t)(NU + w) : (size_t)(2 * NU + NB + (w - NU));
        ((float2*)(outp + dst * FD))[lane] = make_float2(anx, any);
    } else {
        int l = w - n1;
        if (l < NU) ((float2*)(outp + (size_t)l * FD))[lane] = make_float2(anx, any);
        else        items16[(size_t)(l - NU) * FDH + lane] = packbf2(anx, any);
    }
}

// ---------------- BI gather from bf16 items ----------------
__global__ void bi_gather(const int* __restrict__ rowptr, const int* __restrict__ cols,
                          const float* __restrict__ wts, int S1,
                          const uint* __restrict__ items16,
                          float* __restrict__ outb, int nb) {
    int w = (blockIdx.x * blockDim.x + threadIdx.x) >> 6;
    int lane = threadIdx.x & 63;
    if (w >= nb) return;
    int s = rowptr[w], e = rowptr[w + 1];
    float ax = 0.0f, ay = 0.0f;
    int j = s;
    for (; j + 4 <= e; j += 4) {
        int c0 = cols[j], c1 = cols[j + 1], c2 = cols[j + 2], c3 = cols[j + 3];
        float w0 = wts[j - S1], w1 = wts[j + 1 - S1];
        float w2 = wts[j + 2 - S1], w3 = wts[j + 3 - S1];
        uint x0 = items16[(size_t)c0 * FDH + lane];
        uint x1 = items16[(size_t)c1 * FDH + lane];
        uint x2 = items16[(size_t)c2 * FDH + lane];
        uint x3 = items16[(size_t)c3 * FDH + lane];
        float2 f0 = unpackbf2(x0), f1 = unpackbf2(x1);
        float2 f2 = unpackbf2(x2), f3 = unpackbf2(x3);
        ax = fmaf(w0, f0.x, ax); ay = fmaf(w0, f0.y, ay);
        ax = fmaf(w1, f1.x, ax); ay = fmaf(w1, f1.y, ay);
        ax = fmaf(w2, f2.x, ax); ay = fmaf(w2, f2.y, ay);
        ax = fmaf(w3, f3.x, ax); ay = fmaf(w3, f3.y, ay);
    }
    for (; j < e; ++j) {
        float w0 = wts[j - S1];
        float2 f0 = unpackbf2(items16[(size_t)cols[j] * FDH + lane]);
        ax = fmaf(w0, f0.x, ax); ay = fmaf(w0, f0.y, ay);
    }
    ((float2*)(outb + (size_t)w * FD))[lane] = make_float2(ax, ay);
}

extern "C" void kernel_launch(void* const* d_in, const int* in_sizes, int n_in,
                              void* d_out, int out_size, void* d_ws, size_t ws_size,
                              hipStream_t stream) {
    const float* users   = (const float*)d_in[0];
    const float* bundles = (const float*)d_in[1];
    const float* items   = (const float*)d_in[2];
    const float* bi_vals = (const float*)d_in[3];
    const int* ub_u = (const int*)d_in[4];
    const int* ub_b = (const int*)d_in[5];
    const int* ui_u = (const int*)d_in[6];
    const int* ui_i = (const int*)d_in[7];
    const int* bi_b = (const int*)d_in[8];
    const int* bi_i = (const int*)d_in[9];

    const int NU = in_sizes[0] / FD;
    const int NB = in_sizes[1] / FD;
    const int NI = in_sizes[2] / FD;
    const int E_BI = in_sizes[3];
    const int E_UB = in_sizes[4];
    const int E_UI = in_sizes[6];
    float* out = (float*)d_out;

    const int n1 = NU + NB, n2 = NU + NI;
    const int n12 = n1 + n2;
    const int NT = NU + NB + NI;
    const int NN = n12 + NB;                        // total CSR rows
    const int S1 = 2 * E_UB + 2 * E_UI;             // first BI slot / BI rowptr base
    const int TOT = S1 + E_BI;                      // total CSR entries
    const int ETOT = E_UB + E_UI + E_BI;

    // ---- workspace layout ----
    uint* fini16   = (uint*)d_ws;                          // NT*FDH
    uint* facc16   = fini16 + (size_t)NT * FDH;            // n12*FDH
    uint* fX16     = facc16 + (size_t)n12 * FDH;           // n12*FDH
    uint* items16  = fX16 + (size_t)n12 * FDH;             // NI*FDH
    float* normf   = (float*)(items16 + (size_t)NI * FDH); // NT
    float* dinv    = normf + NT;                           // n12
    float* scaled1 = dinv + n12;                           // n12
    float* wts     = scaled1 + n12;                        // E_BI
    int* deg       = (int*)(wts + E_BI);                   // NN+1
    int* rowptr    = deg + (NN + 1);                       // NN+1
    int* head      = rowptr + (NN + 1);                    // NN
    int* bsum      = head + NN;                            // 512
    int* cols      = bsum + 512;                           // TOT
    int2* pairLL   = (int2*)((((size_t)(cols + TOT)) + 15) & ~(size_t)15);  // TOT int2

    dim3 blk(256);
    auto rows_grid = [](int n) { return dim3((unsigned)((n + 3) / 4)); };
    auto thr_grid  = [](int n) { return dim3((unsigned)((n + 255) / 256)); };

    // ---- linked-list CSR build (one atomic pass) + fused feature prep ----
    hipMemsetAsync(head, 0xFF, (size_t)NN * 4, stream);    // head = -1
    int nblk_edges = (ETOT + 255) / 256;
    int nblk_prep  = (NT + 3) / 4;
    passA<<<dim3((unsigned)(nblk_edges + nblk_prep)), blk, 0, stream>>>(
        ub_u, ub_b, ui_u, ui_i, bi_b, bi_i, users, bundles, items,
        E_UB, E_UI, E_BI, NU, NB, n1, n2, NT, nblk_edges,
        head, pairLL, fini16, normf);
    passB<<<thr_grid(NN + 1), blk, 0, stream>>>(head, pairLL, NN, n1, n2, NU, NB,
                                                normf, deg, dinv, scaled1);
    {
        int nelem = NN + 1;
        int nblk = (nelem + SCAN_ELEMS - 1) / SCAN_ELEMS;
        scan_a<<<dim3((unsigned)nblk), dim3(SCAN_TPB), 0, stream>>>(deg, rowptr, bsum, nelem);
        scan_b<<<dim3(1), dim3(512), 0, stream>>>(bsum, nblk);
        scan_c<<<dim3((unsigned)nblk), dim3(SCAN_TPB), 0, stream>>>(rowptr, bsum, nelem);
    }
    passC<<<thr_grid(NN), blk, 0, stream>>>(head, pairLL, rowptr, bi_vals,
                                            NN, n12, S1, cols, wts);

    // ---- Layer 1 (UB + UI fused) ----
    spmm_L1<<<rows_grid(n12), blk, 0, stream>>>(rowptr, cols, dinv, scaled1, normf,
                                                fini16, facc16, fX16, n1, NU, NB, n12);
    // ---- Layer 2 (UB + UI fused) + writeout ----
    spmm_L2<<<rows_grid(n12), blk, 0, stream>>>(rowptr, cols, dinv, fini16,
                                                facc16, fX16, items16, out, n1, NU, NB, n12);
    // ---- BI aggregation ----
    bi_gather<<<rows_grid(NB), blk, 0, stream>>>(rowptr + n12, cols, wts, S1, items16,
        out + (size_t)2 * NU * FD, NB);
}